// Round 4
// baseline (92.531 us; speedup 1.0000x reference)
//
#include <hip/hip_runtime.h>

// out[b] = sum_h [ dot(x1_bh,W1_h) + b1_h + dot(x2_bh,W2_h)
//                  + sum_o x2_bh[o] * dot(W3_h[o,:], x1_bh) ]
// B=16384, HEAD=8, DIM=128.
//
// R4: fix R3's scratch spill (WRITE_SIZE was 150 MB).
//  - Prep kernel splits W3 (512 KB) into bf16 hi/lo in d_ws ONCE ->
//    no B-split VALU in main loop, B fragments load directly as bf16x8.
//  - Main: wave = head, 2 m-tiles (32 samples/block, 512 blocks).
//    acc[2][8] f32x4 = 64 VGPR; peak live ~118 -> fits 128-VGPR budget
//    (launch_bounds(512,4)) -> 2 blocks/CU, no spill.
//  - Split-bf16 3-pass (hi*hi + lo*hi + hi*lo) for fp32-grade accuracy.
// Fragment layouts (m89/m91): A: m=lane&15, k=(lane>>4)*8+j;
//   B: n=lane&15, same k; C/D: col=lane&15, row=(lane>>4)*4+reg.

#define NB 16384
#define NHEAD 8
#define NDIM 128

typedef __attribute__((ext_vector_type(8))) short bf16x8;
typedef __attribute__((ext_vector_type(4))) float f32x4;

__global__ __launch_bounds__(256) void split_w3_kernel(
    const float* __restrict__ W3, short* __restrict__ whi,
    short* __restrict__ wlo)
{
    const int i = blockIdx.x * 256 + threadIdx.x;   // 131072 elements
    const float x = W3[i];
    const unsigned u = __float_as_uint(x);
    const short hi = (short)(u >> 16);
    const float hf = __uint_as_float(u & 0xffff0000u);
    whi[i] = hi;
    wlo[i] = (short)(__float_as_uint(x - hf) >> 16);
}

__device__ __forceinline__ void split8(const float* __restrict__ p,
                                       bf16x8& hi, bf16x8& lo,
                                       float* __restrict__ xf) {
    const float4 a = *reinterpret_cast<const float4*>(p);
    const float4 b = *reinterpret_cast<const float4*>(p + 4);
    xf[0] = a.x; xf[1] = a.y; xf[2] = a.z; xf[3] = a.w;
    xf[4] = b.x; xf[5] = b.y; xf[6] = b.z; xf[7] = b.w;
#pragma unroll
    for (int j = 0; j < 8; ++j) {
        const unsigned u = __float_as_uint(xf[j]);
        hi[j] = (short)(u >> 16);
        const float hf = __uint_as_float(u & 0xffff0000u);
        lo[j] = (short)(__float_as_uint(xf[j] - hf) >> 16);
    }
}

__global__ __launch_bounds__(512, 4) void bilinear_mfma(
    const float* __restrict__ x1, const float* __restrict__ x2,
    const float* __restrict__ W1, const float* __restrict__ b1,
    const float* __restrict__ W2, const short* __restrict__ whi,
    const short* __restrict__ wlo, float* __restrict__ out)
{
    const int tid = threadIdx.x;
    const int w   = tid >> 6;
    const int l   = tid & 63;
    const int h   = __builtin_amdgcn_readfirstlane(w);  // wave = head
    const int lm  = l & 15;    // A-row m / B,C-col n
    const int lg  = l >> 4;    // k-group; C-row group
    const int b0  = blockIdx.x * 32;

    f32x4 acc[2][8];
#pragma unroll
    for (int mt = 0; mt < 2; ++mt)
#pragma unroll
        for (int nt = 0; nt < 8; ++nt) acc[mt][nt] = (f32x4)0.f;

    float t1p[2] = {0.f, 0.f};

    const float* __restrict__ w1base = W1 + h * NDIM;
    const size_t wsrow = ((size_t)h * NDIM + lm) * NDIM;  // + nt*16*NDIM + k0

#pragma unroll
    for (int kk = 0; kk < 4; ++kk) {
        const int k0 = kk * 32 + lg * 8;

        // A fragments (x1 split in-register) + t1 partials (exact fp32)
        bf16x8 ahi[2], alo[2];
        {
            float w1f[8];
            const float4 a = *reinterpret_cast<const float4*>(w1base + k0);
            const float4 b = *reinterpret_cast<const float4*>(w1base + k0 + 4);
            w1f[0] = a.x; w1f[1] = a.y; w1f[2] = a.z; w1f[3] = a.w;
            w1f[4] = b.x; w1f[5] = b.y; w1f[6] = b.z; w1f[7] = b.w;
#pragma unroll
            for (int mt = 0; mt < 2; ++mt) {
                const float* xp = x1
                    + (size_t)(b0 + mt * 16 + lm) * (NHEAD * NDIM)
                    + h * NDIM + k0;
                float xf[8];
                split8(xp, ahi[mt], alo[mt], xf);
#pragma unroll
                for (int j = 0; j < 8; ++j) t1p[mt] += xf[j] * w1f[j];
            }
        }

        // B fragments: pre-split bf16 from ws, direct 16B loads; 6 MFMA/nt
#pragma unroll
        for (int nt = 0; nt < 8; ++nt) {
            const size_t off = wsrow + (size_t)nt * 16 * NDIM + k0;
            const bf16x8 bhi = *reinterpret_cast<const bf16x8*>(whi + off);
            const bf16x8 blo = *reinterpret_cast<const bf16x8*>(wlo + off);
#pragma unroll
            for (int mt = 0; mt < 2; ++mt)
                acc[mt][nt] = __builtin_amdgcn_mfma_f32_16x16x32_bf16(
                    ahi[mt], bhi, acc[mt][nt], 0, 0, 0);
#pragma unroll
            for (int mt = 0; mt < 2; ++mt)
                acc[mt][nt] = __builtin_amdgcn_mfma_f32_16x16x32_bf16(
                    alo[mt], bhi, acc[mt][nt], 0, 0, 0);
#pragma unroll
            for (int mt = 0; mt < 2; ++mt)
                acc[mt][nt] = __builtin_amdgcn_mfma_f32_16x16x32_bf16(
                    ahi[mt], blo, acc[mt][nt], 0, 0, 0);
        }
    }

    // ---- epilogue: contrib[b] = sum_o (P[b,o]+W2[h,o])*x2[b,h,o]; + t1 ----
    __shared__ float pw[NHEAD][32];
    __shared__ float pt[NHEAD][32];

    float w2v[8];
#pragma unroll
    for (int nt = 0; nt < 8; ++nt) w2v[nt] = W2[h * NDIM + nt * 16 + lm];

#pragma unroll
    for (int mt = 0; mt < 2; ++mt) {
        float cr[4];
#pragma unroll
        for (int r = 0; r < 4; ++r) {
            const float* x2p = x2
                + (size_t)(b0 + mt * 16 + lg * 4 + r) * (NHEAD * NDIM)
                + h * NDIM + lm;
            float s = 0.f;
#pragma unroll
            for (int nt = 0; nt < 8; ++nt)
                s += (acc[mt][nt][r] + w2v[nt]) * x2p[nt * 16];
            cr[r] = s;
        }
#pragma unroll
        for (int m = 1; m < 16; m <<= 1)
#pragma unroll
            for (int r = 0; r < 4; ++r) cr[r] += __shfl_xor(cr[r], m, 64);
        if (lm == 0)
#pragma unroll
            for (int r = 0; r < 4; ++r) pw[w][mt * 16 + lg * 4 + r] = cr[r];

        float t = t1p[mt];
        t += __shfl_xor(t, 16, 64);
        t += __shfl_xor(t, 32, 64);
        if (l < 16) pt[w][mt * 16 + l] = t;
    }
    __syncthreads();

    if (w == 0 && l < 32) {
        float s = 0.f;
#pragma unroll
        for (int hh = 0; hh < NHEAD; ++hh)
            s += pw[hh][l] + pt[hh][l] + b1[hh];
        out[b0 + l] = s;
    }
}

extern "C" void kernel_launch(void* const* d_in, const int* in_sizes, int n_in,
                              void* d_out, int out_size, void* d_ws, size_t ws_size,
                              hipStream_t stream) {
    const float* x1 = (const float*)d_in[0];
    const float* x2 = (const float*)d_in[1];
    const float* W1 = (const float*)d_in[2];
    const float* b1 = (const float*)d_in[3];
    const float* W2 = (const float*)d_in[4];
    const float* W3 = (const float*)d_in[5];
    float* out = (float*)d_out;

    short* whi = (short*)d_ws;                       // 256 KB
    short* wlo = whi + (size_t)NHEAD * NDIM * NDIM;  // 256 KB

    split_w3_kernel<<<dim3(NHEAD * NDIM * NDIM / 256), dim3(256), 0, stream>>>(
        W3, whi, wlo);
    bilinear_mfma<<<dim3(NB / 32), dim3(512), 0, stream>>>(
        x1, x2, W1, b1, W2, whi, wlo, out);
}

// Round 5
// 39.259 us; speedup vs baseline: 2.3569x; 2.3569x over previous
//
#include <hip/hip_runtime.h>

// out[b] = sum_h [ dot(x1_bh,W1_h) + b1_h + dot(x2_bh,W2_h)
//                  + sum_o x2_bh[o] * dot(W3_h[o,:], x1_bh) ]
// B=16384, HEAD=8, DIM=128.
//
// R5: kill R4's spill (WRITE_SIZE 120 MB). One HEAD per block; W3_h pre-split
// (bf16 hi/lo, 3-pass split accumulation) AND pre-tiled into MFMA fragment
// order [kk][nt][lane][8] by a prep kernel. Main kernel stages the head's
// 64 KB into LDS once; B-frags come from conflict-free linear ds_read_b128
// (short latency -> compiler doesn't hoist 16-deep like the global version
// did). Per wave: 1 m-tile, acc[8] f32x4 = 32 regs; live set ~100 -> fits the
// 128-reg budget of __launch_bounds__(512,4) -> 2 blocks/CU, no scratch.
// Cross-head sum via fp32 partials in d_ws (+ reduce kernel). ws = 1 MiB:
//   [0, 256K)   whi   fragment-ordered bf16 hi
//   [256K,512K) wlo   fragment-ordered bf16 lo
//   [512K,1M)   psum  float[8][16384]
// Fragment layouts (verified m89/m91): A: m=lane&15, k=(lane>>4)*8+j;
//   B: n=lane&15, same k (B[k][n]=W3[h][n][k]); C/D: col=lane&15,
//   row=(lane>>4)*4+reg.

#define NB 16384
#define NHEAD 8
#define NDIM 128

typedef __attribute__((ext_vector_type(8))) short bf16x8;
typedef __attribute__((ext_vector_type(4))) float f32x4;

// ---- prep: split W3 into bf16 hi/lo, laid out in MFMA B-fragment order ----
// thread t = ((h*4+kk)*8+nt)*64+lane ; writes whi[t*8..t*8+8)
__global__ __launch_bounds__(256) void prep_w3(
    const float* __restrict__ W3, short* __restrict__ whi,
    short* __restrict__ wlo)
{
    const int t    = blockIdx.x * 256 + threadIdx.x;   // 16384 threads
    const int lane = t & 63;
    const int nt   = (t >> 6) & 7;
    const int kk   = (t >> 9) & 3;
    const int h    = t >> 11;
    const int lm   = lane & 15;
    const int lg   = lane >> 4;

    const float* src = W3 + ((size_t)(h * NDIM + nt * 16 + lm)) * NDIM
                          + kk * 32 + lg * 8;
    const float4 a = *reinterpret_cast<const float4*>(src);
    const float4 b = *reinterpret_cast<const float4*>(src + 4);
    float xf[8] = {a.x, a.y, a.z, a.w, b.x, b.y, b.z, b.w};
    bf16x8 hi, lo;
#pragma unroll
    for (int j = 0; j < 8; ++j) {
        const unsigned u = __float_as_uint(xf[j]);
        hi[j] = (short)(u >> 16);
        const float hf = __uint_as_float(u & 0xffff0000u);
        lo[j] = (short)(__float_as_uint(xf[j] - hf) >> 16);
    }
    reinterpret_cast<bf16x8*>(whi)[t] = hi;
    reinterpret_cast<bf16x8*>(wlo)[t] = lo;
}

// ---- main: one head per block, 8 waves x 16 samples = 128 samples ----
__global__ __launch_bounds__(512, 4) void bilinear_mfma(
    const float* __restrict__ x1, const float* __restrict__ x2,
    const float* __restrict__ W1, const float* __restrict__ W2,
    const short* __restrict__ whi, const short* __restrict__ wlo,
    float* __restrict__ psum)
{
    const int tid = threadIdx.x;
    const int w   = tid >> 6;
    const int l   = tid & 63;
    const int lm  = l & 15;
    const int lg  = l >> 4;
    const int h   = blockIdx.y;            // SGPR-uniform head
    const int b0  = blockIdx.x * 128;
    const int bw  = b0 + w * 16;           // wave's 16 samples

    __shared__ short lhi[4][8][512];       // 32 KB, fragment order
    __shared__ short llo[4][8][512];       // 32 KB
    __shared__ float pw[8][16];
    __shared__ float pt[8][16];

    // stage this head's pre-split W3 (64 KB) into LDS, linear copy
    {
        const float4* shi = reinterpret_cast<const float4*>(whi + (size_t)h * 16384);
        const float4* slo = reinterpret_cast<const float4*>(wlo + (size_t)h * 16384);
        float4* dhi = reinterpret_cast<float4*>(&lhi[0][0][0]);
        float4* dlo = reinterpret_cast<float4*>(&llo[0][0][0]);
#pragma unroll
        for (int i = 0; i < 4; ++i) {      // 2048 float4 per buffer
            dhi[i * 512 + tid] = shi[i * 512 + tid];
            dlo[i * 512 + tid] = slo[i * 512 + tid];
        }
    }
    __syncthreads();

    f32x4 acc[8];
#pragma unroll
    for (int nt = 0; nt < 8; ++nt) acc[nt] = (f32x4)0.f;
    float t1 = 0.f;

    const float* __restrict__ w1base = W1 + h * NDIM;

#pragma unroll
    for (int kk = 0; kk < 4; ++kk) {
        const int k0 = kk * 32 + lg * 8;

        // A-fragment: split x1 in-register; t1 from exact fp32 values
        bf16x8 ahi, alo;
        {
            const float* xp = x1 + (size_t)(bw + lm) * (NHEAD * NDIM)
                               + h * NDIM + k0;
            const float4 a  = *reinterpret_cast<const float4*>(xp);
            const float4 b  = *reinterpret_cast<const float4*>(xp + 4);
            const float4 wa = *reinterpret_cast<const float4*>(w1base + k0);
            const float4 wb = *reinterpret_cast<const float4*>(w1base + k0 + 4);
            float xf[8]  = {a.x, a.y, a.z, a.w, b.x, b.y, b.z, b.w};
            float w1f[8] = {wa.x, wa.y, wa.z, wa.w, wb.x, wb.y, wb.z, wb.w};
#pragma unroll
            for (int j = 0; j < 8; ++j) {
                const unsigned u = __float_as_uint(xf[j]);
                ahi[j] = (short)(u >> 16);
                const float hf = __uint_as_float(u & 0xffff0000u);
                alo[j] = (short)(__float_as_uint(xf[j] - hf) >> 16);
                t1 += xf[j] * w1f[j];
            }
        }

        // B-fragments from LDS (conflict-free 1KB/wave linear reads)
#pragma unroll
        for (int nt = 0; nt < 8; ++nt) {
            const bf16x8 bhi = *reinterpret_cast<const bf16x8*>(&lhi[kk][nt][l * 8]);
            const bf16x8 blo = *reinterpret_cast<const bf16x8*>(&llo[kk][nt][l * 8]);
            acc[nt] = __builtin_amdgcn_mfma_f32_16x16x32_bf16(ahi, bhi, acc[nt], 0, 0, 0);
            acc[nt] = __builtin_amdgcn_mfma_f32_16x16x32_bf16(alo, bhi, acc[nt], 0, 0, 0);
            acc[nt] = __builtin_amdgcn_mfma_f32_16x16x32_bf16(ahi, blo, acc[nt], 0, 0, 0);
        }
    }

    // ---- epilogue: sum_o (P[b,o]+W2[h,o]) * x2[b,h,o] ----
    float w2v[8];
#pragma unroll
    for (int nt = 0; nt < 8; ++nt) w2v[nt] = W2[h * NDIM + nt * 16 + lm];

    float cr[4];
#pragma unroll
    for (int r = 0; r < 4; ++r) {
        const float* x2p = x2 + (size_t)(bw + lg * 4 + r) * (NHEAD * NDIM)
                            + h * NDIM + lm;
        float s = 0.f;
#pragma unroll
        for (int nt = 0; nt < 8; ++nt)
            s += (acc[nt][r] + w2v[nt]) * x2p[nt * 16];
        cr[r] = s;
    }
#pragma unroll
    for (int m = 1; m < 16; m <<= 1)
#pragma unroll
        for (int r = 0; r < 4; ++r) cr[r] += __shfl_xor(cr[r], m, 64);
    if (lm == 0)
#pragma unroll
        for (int r = 0; r < 4; ++r) pw[w][lg * 4 + r] = cr[r];

    float t = t1;
    t += __shfl_xor(t, 16, 64);
    t += __shfl_xor(t, 32, 64);
    if (l < 16) pt[w][l] = t;
    __syncthreads();

    if (tid < 128)
        psum[(size_t)h * NB + b0 + tid] = pw[tid >> 4][tid & 15]
                                        + pt[tid >> 4][tid & 15];
}

__global__ __launch_bounds__(256) void bilinear_reduce(
    const float* __restrict__ psum, const float* __restrict__ b1,
    float* __restrict__ out)
{
    const int i = blockIdx.x * 256 + threadIdx.x;
    float bs = 0.f;
#pragma unroll
    for (int hh = 0; hh < NHEAD; ++hh) bs += b1[hh];
    float s = bs;
#pragma unroll
    for (int hh = 0; hh < NHEAD; ++hh) s += psum[(size_t)hh * NB + i];
    out[i] = s;
}

extern "C" void kernel_launch(void* const* d_in, const int* in_sizes, int n_in,
                              void* d_out, int out_size, void* d_ws, size_t ws_size,
                              hipStream_t stream) {
    const float* x1 = (const float*)d_in[0];
    const float* x2 = (const float*)d_in[1];
    const float* W1 = (const float*)d_in[2];
    const float* b1 = (const float*)d_in[3];
    const float* W2 = (const float*)d_in[4];
    const float* W3 = (const float*)d_in[5];
    float* out = (float*)d_out;

    short* whi = (short*)d_ws;                          // 256 KB
    short* wlo = whi + (size_t)NHEAD * NDIM * NDIM;     // 256 KB
    float* psum = (float*)((char*)d_ws + 512 * 1024);   // 512 KB

    prep_w3<<<dim3(64), dim3(256), 0, stream>>>(W3, whi, wlo);
    bilinear_mfma<<<dim3(NB / 128, NHEAD), dim3(512), 0, stream>>>(
        x1, x2, W1, W2, whi, wlo, psum);
    bilinear_reduce<<<dim3(NB / 256), dim3(256), 0, stream>>>(psum, b1, out);
}